// Round 1
// baseline (1406.696 us; speedup 1.0000x reference)
//
#include <hip/hip_runtime.h>
#include <hip/hip_bf16.h>

#define Nn 50000
#define Ee 600000
#define Dd 128
#define Bb 4
#define Rr 100
#define EPSc 1e-5f

// ---------------- wcat: rearrange V [B,D,D] -> Wcat [D, B*D] ----------------
__global__ __launch_bounds__(256) void wcat_k(const float* __restrict__ V,
                                              float* __restrict__ wcat) {
    int i = blockIdx.x * 256 + threadIdx.x;      // over 128*512
    if (i >= Dd * Bb * Dd) return;
    int k = i >> 9;          // 0..127
    int c = i & 511;         // 0..511
    int b = c >> 7;
    int o = c & 127;
    wcat[i] = V[b * (Dd * Dd) + k * Dd + o];
}

// ---------------- tiled fp32 GEMM: OUT[rows,NC] = X[rows,128] @ W[128,NC] ---
// FUSE: OUT = relu(X@W + AGG + bias) (in-place OUT==AGG allowed)
template <int NC, bool FUSE>
__global__ __launch_bounds__(256) void gemm_k(const float* __restrict__ X,
                                              const float* __restrict__ W,
                                              float* __restrict__ OUT,
                                              const float* __restrict__ AGG,
                                              const float* __restrict__ bias,
                                              int rows) {
    __shared__ float xs[32][64];   // [k][r] transposed
    __shared__ float wsh[32][64];  // [k][c]
    const int tid = threadIdx.x;
    const int bm = blockIdx.x * 64;
    const int bn = blockIdx.y * 64;
    const int tc = (tid & 15) * 4;
    const int tr = (tid >> 4) * 4;
    const int lrow = tid >> 2, lk = (tid & 3) * 8;
    const int wk = tid >> 3, wc = (tid & 7) * 8;
    float acc[4][4] = {};

    for (int k0 = 0; k0 < 128; k0 += 32) {
        __syncthreads();
        int grow = bm + lrow;
        if (grow < rows) {
            const float* xp = X + (size_t)grow * 128 + k0 + lk;
#pragma unroll
            for (int j = 0; j < 8; j++) xs[lk + j][lrow] = xp[j];
        } else {
#pragma unroll
            for (int j = 0; j < 8; j++) xs[lk + j][lrow] = 0.f;
        }
        const float* wp = W + (size_t)(k0 + wk) * NC + bn + wc;
#pragma unroll
        for (int j = 0; j < 8; j++) wsh[wk][wc + j] = wp[j];
        __syncthreads();
#pragma unroll
        for (int k = 0; k < 32; k++) {
            float4 xv = *(const float4*)&xs[k][tr];
            float4 wv = *(const float4*)&wsh[k][tc];
            acc[0][0] += xv.x * wv.x; acc[0][1] += xv.x * wv.y;
            acc[0][2] += xv.x * wv.z; acc[0][3] += xv.x * wv.w;
            acc[1][0] += xv.y * wv.x; acc[1][1] += xv.y * wv.y;
            acc[1][2] += xv.y * wv.z; acc[1][3] += xv.y * wv.w;
            acc[2][0] += xv.z * wv.x; acc[2][1] += xv.z * wv.y;
            acc[2][2] += xv.z * wv.z; acc[2][3] += xv.z * wv.w;
            acc[3][0] += xv.w * wv.x; acc[3][1] += xv.w * wv.y;
            acc[3][2] += xv.w * wv.z; acc[3][3] += xv.w * wv.w;
        }
    }
#pragma unroll
    for (int i = 0; i < 4; i++) {
        int r = bm + tr + i;
        if (r >= rows) break;
        size_t off = (size_t)r * NC + bn + tc;
        float4 v;
        v.x = acc[i][0]; v.y = acc[i][1]; v.z = acc[i][2]; v.w = acc[i][3];
        if (FUSE) {
            float4 a = *(const float4*)&AGG[off];
            v.x = fmaxf(v.x + a.x + bias[bn + tc + 0], 0.f);
            v.y = fmaxf(v.y + a.y + bias[bn + tc + 1], 0.f);
            v.z = fmaxf(v.z + a.z + bias[bn + tc + 2], 0.f);
            v.w = fmaxf(v.w + a.w + bias[bn + tc + 3], 0.f);
        }
        *(float4*)&OUT[off] = v;
    }
}

// ---------------- edge messages: agg[dst] += sum_b comb[etype,b]*xb[src,b,:] -
__global__ __launch_bounds__(256) void edge_k(const float* __restrict__ xb,
                                              const int* __restrict__ src,
                                              const int* __restrict__ dst,
                                              const int* __restrict__ et,
                                              const float* __restrict__ comb,
                                              float* __restrict__ agg) {
    int e = blockIdx.x * 4 + (threadIdx.x >> 6);
    int lane = threadIdx.x & 63;
    int s = src[e], d = dst[e], r = et[e];
    const float* cb = comb + r * 4;
    float c0 = cb[0], c1 = cb[1], c2 = cb[2], c3 = cb[3];
    const float2* xr = (const float2*)(xb + (size_t)s * (Bb * Dd));
    float2 v0 = xr[lane];
    float2 v1 = xr[64 + lane];
    float2 v2 = xr[128 + lane];
    float2 v3 = xr[192 + lane];
    float mx = c0 * v0.x + c1 * v1.x + c2 * v2.x + c3 * v3.x;
    float my = c0 * v0.y + c1 * v1.y + c2 * v2.y + c3 * v3.y;
    float* ap = agg + (size_t)d * Dd + lane * 2;
    unsafeAtomicAdd(ap, mx);
    unsafeAtomicAdd(ap + 1, my);
}

// ---------------- BN stats: column sum / sumsq --------------------------------
__global__ __launch_bounds__(256) void stats_k(const float* __restrict__ h,
                                               float* __restrict__ stats,
                                               int rows) {
    int c = threadIdx.x & 127;
    int rstart = blockIdx.x * 2 + (threadIdx.x >> 7);
    float s = 0.f, s2 = 0.f;
    for (int r = rstart; r < rows; r += gridDim.x * 2) {
        float v = h[(size_t)r * Dd + c];
        s += v;
        s2 += v * v;
    }
    unsafeAtomicAdd(&stats[c], s);
    unsafeAtomicAdd(&stats[Dd + c], s2);
}

// ---------------- BN normalize ------------------------------------------------
__global__ __launch_bounds__(256) void norm_k(const float* __restrict__ h,
                                              const float* __restrict__ stats,
                                              const float* __restrict__ gamma,
                                              const float* __restrict__ beta,
                                              float* __restrict__ out,
                                              int rows) {
    const float invN = 1.0f / (float)rows;
    int total = rows * 32;  // float4 units
    for (int i = blockIdx.x * blockDim.x + threadIdx.x; i < total;
         i += gridDim.x * blockDim.x) {
        int c = (i & 31) * 4;
        float4 v = ((const float4*)h)[i];
        float4 o;
        {
            float mu = stats[c + 0] * invN;
            float var = stats[Dd + c + 0] * invN - mu * mu;
            o.x = gamma[c + 0] * (v.x - mu) * rsqrtf(var + EPSc) + beta[c + 0];
        }
        {
            float mu = stats[c + 1] * invN;
            float var = stats[Dd + c + 1] * invN - mu * mu;
            o.y = gamma[c + 1] * (v.y - mu) * rsqrtf(var + EPSc) + beta[c + 1];
        }
        {
            float mu = stats[c + 2] * invN;
            float var = stats[Dd + c + 2] * invN - mu * mu;
            o.z = gamma[c + 2] * (v.z - mu) * rsqrtf(var + EPSc) + beta[c + 2];
        }
        {
            float mu = stats[c + 3] * invN;
            float var = stats[Dd + c + 3] * invN - mu * mu;
            o.w = gamma[c + 3] * (v.w - mu) * rsqrtf(var + EPSc) + beta[c + 3];
        }
        ((float4*)out)[i] = o;
    }
}

// ---------------- launch ------------------------------------------------------
extern "C" void kernel_launch(void* const* d_in, const int* in_sizes, int n_in,
                              void* d_out, int out_size, void* d_ws, size_t ws_size,
                              hipStream_t stream) {
    const float* feat = (const float*)d_in[0];
    const int* src = (const int*)d_in[1];
    const int* dst = (const int*)d_in[2];
    const int* et = (const int*)d_in[3];

    float* out = (float*)d_out;

    // workspace layout
    float* xb = (float*)d_ws;                         // N*512 floats
    float* agg = xb + (size_t)Nn * (Bb * Dd);         // N*128 floats
    float* wcat = agg + (size_t)Nn * Dd;              // 128*512 floats
    float* stats = wcat + (size_t)Dd * Bb * Dd;       // 256 floats

    const int gemm_gx = (Nn + 63) / 64;               // 782

    for (int l = 0; l < 2; l++) {
        const float* V = (const float*)d_in[4 + 6 * l + 0];
        const float* comb = (const float*)d_in[4 + 6 * l + 1];
        const float* loop = (const float*)d_in[4 + 6 * l + 2];
        const float* bias = (const float*)d_in[4 + 6 * l + 3];
        const float* gamma = (const float*)d_in[4 + 6 * l + 4];
        const float* beta = (const float*)d_in[4 + 6 * l + 5];
        const float* xin = (l == 0) ? feat : out;

        hipMemsetAsync(agg, 0, (size_t)Nn * Dd * sizeof(float), stream);
        hipMemsetAsync(stats, 0, 2 * Dd * sizeof(float), stream);

        wcat_k<<<(Dd * Bb * Dd + 255) / 256, 256, 0, stream>>>(V, wcat);
        gemm_k<512, false><<<dim3(gemm_gx, 8), 256, 0, stream>>>(
            xin, wcat, xb, nullptr, nullptr, Nn);
        edge_k<<<Ee / 4, 256, 0, stream>>>(xb, src, dst, et, comb, agg);
        gemm_k<128, true><<<dim3(gemm_gx, 2), 256, 0, stream>>>(
            xin, loop, agg, agg, bias, Nn);
        stats_k<<<1024, 256, 0, stream>>>(agg, stats, Nn);
        norm_k<<<2048, 256, 0, stream>>>(agg, stats, gamma, beta, out, Nn);
    }
}

// Round 3
// 811.208 us; speedup vs baseline: 1.7341x; 1.7341x over previous
//
#include <hip/hip_runtime.h>
#include <hip/hip_bf16.h>

#define Nn 50000
#define Ee 600000
#define Dd 128
#define EPSc 1e-5f

// ---------------- CSR build: histogram over dst ------------------------------
__global__ __launch_bounds__(256) void hist_k(const int* __restrict__ dst,
                                              int* __restrict__ cnt) {
    int e = blockIdx.x * 256 + threadIdx.x;
    if (e < Ee) atomicAdd(&cnt[dst[e]], 1);
}

// ---------------- CSR build: exclusive scan (single block, wave-scan) --------
__global__ __launch_bounds__(1024) void scan_k(const int* __restrict__ cnt,
                                               int* __restrict__ rowp) {
    __shared__ int wsum[16];
    __shared__ int carry_s;
    const int t = threadIdx.x, lane = t & 63, w = t >> 6;
    if (t == 0) { carry_s = 0; rowp[0] = 0; }
    __syncthreads();
    for (int base = 0; base < Nn; base += 1024) {
        int v = (base + t < Nn) ? cnt[base + t] : 0;
        int incl = v;
#pragma unroll
        for (int off = 1; off < 64; off <<= 1) {
            int u = __shfl_up(incl, off, 64);
            if (lane >= off) incl += u;
        }
        if (lane == 63) wsum[w] = incl;
        __syncthreads();
        if (t == 0) {
            int run = carry_s;
#pragma unroll
            for (int i = 0; i < 16; i++) { int s = wsum[i]; wsum[i] = run; run += s; }
            carry_s = run;
        }
        __syncthreads();
        if (base + t < Nn) rowp[base + t + 1] = wsum[w] + incl;
        __syncthreads();
    }
}

// ---------------- CSR build: scatter edges to sorted order -------------------
__global__ __launch_bounds__(256) void scatter_k(const int* __restrict__ src,
                                                 const int* __restrict__ dst,
                                                 const int* __restrict__ et,
                                                 int* __restrict__ cursor,
                                                 int2* __restrict__ se) {
    int e = blockIdx.x * 256 + threadIdx.x;
    if (e < Ee) {
        int pos = atomicAdd(&cursor[dst[e]], 1);
        se[pos] = make_int2(src[e], et[e]);
    }
}

// ---------------- per-node aggregation: yb[n,b,:] = sum_e comb[et,b]*x[src] --
__global__ __launch_bounds__(256) void agg_k(const float* __restrict__ x,
                                             const int2* __restrict__ se,
                                             const int* __restrict__ rowp,
                                             const float* __restrict__ comb,
                                             float* __restrict__ yb) {
    const int node = blockIdx.x * 4 + (threadIdx.x >> 6);
    const int lane = threadIdx.x & 63;
    const int beg = rowp[node], end = rowp[node + 1];
    float2 a0 = {0.f, 0.f}, a1 = {0.f, 0.f}, a2 = {0.f, 0.f}, a3 = {0.f, 0.f};
    int2 rn;
    float2 xn;
    if (beg < end) {
        rn = se[beg];
        xn = ((const float2*)(x + (size_t)rn.x * Dd))[lane];
    }
    for (int e = beg; e < end; e++) {
        const int2 rc = rn;
        const float2 xv = xn;
        if (e + 1 < end) {
            rn = se[e + 1];
            xn = ((const float2*)(x + (size_t)rn.x * Dd))[lane];
        }
        const float4 c = ((const float4*)comb)[rc.y];
        a0.x += c.x * xv.x; a0.y += c.x * xv.y;
        a1.x += c.y * xv.x; a1.y += c.y * xv.y;
        a2.x += c.z * xv.x; a2.y += c.z * xv.y;
        a3.x += c.w * xv.x; a3.y += c.w * xv.y;
    }
    float2* yp = (float2*)(yb + (size_t)node * 512);
    yp[lane] = a0;
    yp[64 + lane] = a1;
    yp[128 + lane] = a2;
    yp[192 + lane] = a3;
}

// ---------------- fused GEMM: h = relu(yb@V + x@Wl + bias) -------------------
// yb [N,512], V flat [512,128], x [N,128], Wl [128,128] -> OUT [N,128].
// One block = 64 rows x ALL 128 cols (so xin==OUT in-place is race-free:
// this block is the only reader of x rows [bm,bm+64) and only writer of the
// same out rows; last x staging is ordered before any out write by the final
// __syncthreads()). 128 threads, 8x8 microtile.
__global__ __launch_bounds__(128) void gemm_fused_k(const float* __restrict__ yb,
                                                    const float* __restrict__ V,
                                                    const float* __restrict__ x,
                                                    const float* __restrict__ Wl,
                                                    const float* __restrict__ bias,
                                                    float* __restrict__ OUT) {
    __shared__ float xs[32][64];    // [k][row] (transposed)
    __shared__ float wsh[32][128];  // [k][col], col XOR-4 swizzled in upper half
    const int tid = threadIdx.x;    // 0..127
    const int bm = blockIdx.x * 64;
    const int tr = (tid >> 4) * 8;  // 8 row-groups * 8 = 64 rows
    const int tc = (tid & 15) * 8;  // 16 col-groups * 8 = 128 cols
    const int scw = (tc & 64) ? 4 : 0;
    const int sc0 = tc ^ scw;       // physical col of logical [tc..tc+4)
    const int sc1 = (tc + 4) ^ scw; // physical col of logical [tc+4..tc+8)
    // X^T stage: thread -> row tid>>1, k-halfchunk (tid&1)*16
    const int lrow = tid >> 1, lk = (tid & 1) * 16;
    const int grow = bm + lrow;
    // W stage: 2 rows per pass (one per wave), 64 lanes * float2 = 128 cols
    const int wrow_off = tid >> 6;        // 0 or 1
    const int wcol = (tid & 63) * 2;      // logical col
    const int wcs = wcol ^ ((wcol & 64) ? 4 : 0);  // physical col

    float acc[8][8] = {};

    for (int k0 = 0; k0 < 640; k0 += 32) {
        const bool part1 = (k0 < 512);
        __syncthreads();
        // ---- stage X^T tile ----
        {
            float tmp[16];
            if (grow < Nn) {
                const float* xp = part1 ? (yb + (size_t)grow * 512 + k0 + lk)
                                        : (x + (size_t)grow * 128 + (k0 - 512) + lk);
#pragma unroll
                for (int q = 0; q < 4; q++)
                    *(float4*)&tmp[q * 4] = *(const float4*)&xp[q * 4];
            } else {
#pragma unroll
                for (int j = 0; j < 16; j++) tmp[j] = 0.f;
            }
#pragma unroll
            for (int j = 0; j < 16; j++) xs[lk + j][lrow] = tmp[j];
        }
        // ---- stage W tile (rows of V-flat / Wl are contiguous 128 floats) ----
#pragma unroll
        for (int j = 0; j < 16; j++) {
            const int row = j * 2 + wrow_off;
            const float* wp = part1 ? (V + (size_t)(k0 + row) * 128)
                                    : (Wl + (size_t)(k0 - 512 + row) * 128);
            *(float2*)&wsh[row][wcs] = *(const float2*)&wp[wcol];
        }
        __syncthreads();
        // ---- compute ----
#pragma unroll
        for (int k = 0; k < 32; k++) {
            float4 x0 = *(const float4*)&xs[k][tr];
            float4 x1 = *(const float4*)&xs[k][tr + 4];
            float4 w0 = *(const float4*)&wsh[k][sc0];
            float4 w1 = *(const float4*)&wsh[k][sc1];
            float xv[8] = {x0.x, x0.y, x0.z, x0.w, x1.x, x1.y, x1.z, x1.w};
            float wv[8] = {w0.x, w0.y, w0.z, w0.w, w1.x, w1.y, w1.z, w1.w};
#pragma unroll
            for (int i = 0; i < 8; i++)
#pragma unroll
                for (int j = 0; j < 8; j++) acc[i][j] += xv[i] * wv[j];
        }
    }
    // ---- epilogue: + bias, relu, store ----
    float4 b0 = *(const float4*)&bias[tc];
    float4 b1 = *(const float4*)&bias[tc + 4];
#pragma unroll
    for (int i = 0; i < 8; i++) {
        const int r = bm + tr + i;
        if (r < Nn) {
            float4 o0, o1;
            o0.x = fmaxf(acc[i][0] + b0.x, 0.f);
            o0.y = fmaxf(acc[i][1] + b0.y, 0.f);
            o0.z = fmaxf(acc[i][2] + b0.z, 0.f);
            o0.w = fmaxf(acc[i][3] + b0.w, 0.f);
            o1.x = fmaxf(acc[i][4] + b1.x, 0.f);
            o1.y = fmaxf(acc[i][5] + b1.y, 0.f);
            o1.z = fmaxf(acc[i][6] + b1.z, 0.f);
            o1.w = fmaxf(acc[i][7] + b1.w, 0.f);
            *(float4*)&OUT[(size_t)r * 128 + tc] = o0;
            *(float4*)&OUT[(size_t)r * 128 + tc + 4] = o1;
        }
    }
}

// ---------------- BN stats: column sum / sumsq -------------------------------
__global__ __launch_bounds__(256) void stats_k(const float* __restrict__ h,
                                               float* __restrict__ stats) {
    int c = threadIdx.x & 127;
    int rstart = blockIdx.x * 2 + (threadIdx.x >> 7);
    float s = 0.f, s2 = 0.f;
    for (int r = rstart; r < Nn; r += gridDim.x * 2) {
        float v = h[(size_t)r * Dd + c];
        s += v;
        s2 += v * v;
    }
    unsafeAtomicAdd(&stats[c], s);
    unsafeAtomicAdd(&stats[Dd + c], s2);
}

// ---------------- BN normalize (in-place safe) -------------------------------
__global__ __launch_bounds__(256) void norm_k(const float* __restrict__ h,
                                              const float* __restrict__ stats,
                                              const float* __restrict__ gamma,
                                              const float* __restrict__ beta,
                                              float* __restrict__ out) {
    const float invN = 1.0f / (float)Nn;
    int total = Nn * 32;  // float4 units
    for (int i = blockIdx.x * blockDim.x + threadIdx.x; i < total;
         i += gridDim.x * blockDim.x) {
        int c = (i & 31) * 4;
        float4 v = ((const float4*)h)[i];
        float4 o;
        {
            float mu = stats[c + 0] * invN;
            float var = stats[Dd + c + 0] * invN - mu * mu;
            o.x = gamma[c + 0] * (v.x - mu) * rsqrtf(var + EPSc) + beta[c + 0];
        }
        {
            float mu = stats[c + 1] * invN;
            float var = stats[Dd + c + 1] * invN - mu * mu;
            o.y = gamma[c + 1] * (v.y - mu) * rsqrtf(var + EPSc) + beta[c + 1];
        }
        {
            float mu = stats[c + 2] * invN;
            float var = stats[Dd + c + 2] * invN - mu * mu;
            o.z = gamma[c + 2] * (v.z - mu) * rsqrtf(var + EPSc) + beta[c + 2];
        }
        {
            float mu = stats[c + 3] * invN;
            float var = stats[Dd + c + 3] * invN - mu * mu;
            o.w = gamma[c + 3] * (v.w - mu) * rsqrtf(var + EPSc) + beta[c + 3];
        }
        ((float4*)out)[i] = o;
    }
}

// ---------------- launch -----------------------------------------------------
extern "C" void kernel_launch(void* const* d_in, const int* in_sizes, int n_in,
                              void* d_out, int out_size, void* d_ws, size_t ws_size,
                              hipStream_t stream) {
    const float* feat = (const float*)d_in[0];
    const int* src = (const int*)d_in[1];
    const int* dst = (const int*)d_in[2];
    const int* et = (const int*)d_in[3];
    float* out = (float*)d_out;

    // workspace layout (~107.4 MB)
    char* p = (char*)d_ws;
    float* yb = (float*)p;          p += (size_t)Nn * 512 * 4;              // 102.4 MB
    int* rowp = (int*)p;            p += (((size_t)(Nn + 1) * 4) + 7) & ~7ull;
    int2* se = (int2*)p;            p += (size_t)Ee * 8;                    // 4.8 MB
    float* stats = (float*)p;
    int* cursor = (int*)yb;  // dead before agg_k overwrites yb

    // ---- build CSR once (same graph both layers) ----
    hipMemsetAsync(cursor, 0, (size_t)Nn * 4, stream);
    hist_k<<<(Ee + 255) / 256, 256, 0, stream>>>(dst, cursor);
    scan_k<<<1, 1024, 0, stream>>>(cursor, rowp);
    hipMemcpyAsync(cursor, rowp, (size_t)Nn * 4, hipMemcpyDeviceToDevice, stream);
    scatter_k<<<(Ee + 255) / 256, 256, 0, stream>>>(src, dst, et, cursor, se);

    const int gemm_gx = (Nn + 63) / 64;  // 782

    for (int l = 0; l < 2; l++) {
        const float* V = (const float*)d_in[4 + 6 * l + 0];
        const float* comb = (const float*)d_in[4 + 6 * l + 1];
        const float* loop = (const float*)d_in[4 + 6 * l + 2];
        const float* bias = (const float*)d_in[4 + 6 * l + 3];
        const float* gamma = (const float*)d_in[4 + 6 * l + 4];
        const float* beta = (const float*)d_in[4 + 6 * l + 5];
        const float* xin = (l == 0) ? feat : out;

        agg_k<<<(Nn + 3) / 4, 256, 0, stream>>>(xin, se, rowp, comb, yb);
        hipMemsetAsync(stats, 0, 2 * Dd * sizeof(float), stream);
        gemm_fused_k<<<gemm_gx, 128, 0, stream>>>(yb, V, xin, loop, bias, out);
        stats_k<<<1024, 256, 0, stream>>>(out, stats);
        norm_k<<<2048, 256, 0, stream>>>(out, stats, gamma, beta, out);
    }
}

// Round 4
// 477.803 us; speedup vs baseline: 2.9441x; 1.6978x over previous
//
#include <hip/hip_runtime.h>
#include <hip/hip_bf16.h>

#define Nn 50000
#define Ee 600000
#define Dd 128
#define EPSc 1e-5f

typedef unsigned int u32;
typedef unsigned short u16;
typedef short s16x8 __attribute__((ext_vector_type(8)));
typedef float f32x4 __attribute__((ext_vector_type(4)));

__device__ inline float bf2f(u32 lo16) { return __uint_as_float(lo16 << 16); }
__device__ inline u16 f2bf(float f) {
    u32 b = __float_as_uint(f);
    return (u16)((b + 0x7fffu + ((b >> 16) & 1u)) >> 16);  // RTN-even
}
__device__ inline void gload16(const void* g, void* l) {
    __builtin_amdgcn_global_load_lds(
        (const __attribute__((address_space(1))) u32*)g,
        (__attribute__((address_space(3))) u32*)l, 16, 0, 0);
}

// ---------------- CSR build ----------------
__global__ __launch_bounds__(256) void hist_k(const int* __restrict__ dst,
                                              int* __restrict__ cnt) {
    int e = blockIdx.x * 256 + threadIdx.x;
    if (e < Ee) atomicAdd(&cnt[dst[e]], 1);
}

__global__ __launch_bounds__(1024) void scan_k(const int* __restrict__ cnt,
                                               int* __restrict__ rowp) {
    __shared__ int wsum[16];
    __shared__ int carry_s;
    const int t = threadIdx.x, lane = t & 63, w = t >> 6;
    if (t == 0) { carry_s = 0; rowp[0] = 0; }
    __syncthreads();
    for (int base = 0; base < Nn; base += 1024) {
        int v = (base + t < Nn) ? cnt[base + t] : 0;
        int incl = v;
#pragma unroll
        for (int off = 1; off < 64; off <<= 1) {
            int u = __shfl_up(incl, off, 64);
            if (lane >= off) incl += u;
        }
        if (lane == 63) wsum[w] = incl;
        __syncthreads();
        if (t == 0) {
            int run = carry_s;
#pragma unroll
            for (int i = 0; i < 16; i++) { int s = wsum[i]; wsum[i] = run; run += s; }
            carry_s = run;
        }
        __syncthreads();
        if (base + t < Nn) rowp[base + t + 1] = wsum[w] + incl;
        __syncthreads();
    }
}

__global__ __launch_bounds__(256) void scatter_k(const int* __restrict__ src,
                                                 const int* __restrict__ dst,
                                                 const int* __restrict__ et,
                                                 int* __restrict__ cursor,
                                                 int2* __restrict__ se) {
    int e = blockIdx.x * 256 + threadIdx.x;
    if (e < Ee) {
        int pos = atomicAdd(&cursor[dst[e]], 1);
        se[pos] = make_int2(src[e], et[e]);
    }
}

// ---------------- fp32 -> bf16 convert ----------------
__global__ __launch_bounds__(256) void conv_k(const float* __restrict__ in,
                                              u16* __restrict__ out) {
    const int total = Nn * 32;
    for (int i = blockIdx.x * 256 + threadIdx.x; i < total; i += gridDim.x * 256) {
        float4 v = ((const float4*)in)[i];
        ((ushort4*)out)[i] = make_ushort4(f2bf(v.x), f2bf(v.y), f2bf(v.z), f2bf(v.w));
    }
}

// ---------------- weight prep: Wt[c][k] = W[k][c] in bf16, k: V(512)|loop(128)
__global__ __launch_bounds__(256) void wprep_k(const float* __restrict__ V,
                                               const float* __restrict__ loop,
                                               u16* __restrict__ Wt) {
    int i = blockIdx.x * 256 + threadIdx.x;  // 128*640
    if (i >= 128 * 640) return;
    int c = i / 640, k = i - c * 640;
    float v = (k < 512) ? V[(size_t)k * 128 + c] : loop[(size_t)(k - 512) * 128 + c];
    Wt[i] = f2bf(v);
}

// ---------------- aggregation: yb16[n,b,:] = sum_e comb[et,b]*x16[src] -------
__global__ __launch_bounds__(256) void agg_k(const u16* __restrict__ x16,
                                             const int2* __restrict__ se,
                                             const int* __restrict__ rowp,
                                             const float* __restrict__ comb,
                                             u16* __restrict__ yb16) {
    const int node = blockIdx.x * 4 + (threadIdx.x >> 6);
    const int lane = threadIdx.x & 63;
    const int beg = rowp[node], end = rowp[node + 1];
    float a0x = 0.f, a0y = 0.f, a1x = 0.f, a1y = 0.f;
    float a2x = 0.f, a2y = 0.f, a3x = 0.f, a3y = 0.f;
    int2 rn;
    u32 xn;
    if (beg < end) {
        rn = se[beg];
        xn = *(const u32*)&x16[(size_t)rn.x * 128 + lane * 2];
    }
    for (int e = beg; e < end; e++) {
        const int2 rc = rn;
        const u32 xv = xn;
        if (e + 1 < end) {
            rn = se[e + 1];
            xn = *(const u32*)&x16[(size_t)rn.x * 128 + lane * 2];
        }
        const float4 c = ((const float4*)comb)[rc.y];
        const float fx = bf2f(xv & 0xffffu), fy = bf2f(xv >> 16);
        a0x += c.x * fx; a0y += c.x * fy;
        a1x += c.y * fx; a1y += c.y * fy;
        a2x += c.z * fx; a2y += c.z * fy;
        a3x += c.w * fx; a3y += c.w * fy;
    }
    u32* yp = (u32*)(yb16 + (size_t)node * 512);
    yp[lane]       = (u32)f2bf(a0x) | ((u32)f2bf(a0y) << 16);
    yp[64 + lane]  = (u32)f2bf(a1x) | ((u32)f2bf(a1y) << 16);
    yp[128 + lane] = (u32)f2bf(a2x) | ((u32)f2bf(a2y) << 16);
    yp[192 + lane] = (u32)f2bf(a3x) | ((u32)f2bf(a3y) << 16);
}

// ---------------- MFMA GEMM: OUT = relu([yb16|x16] @ Wt^T + bias) ------------
// A [N,640] bf16 (concat), B via Wt [128 cols][640 k] bf16. BM=128,BN=128,BK=32,
// 4 waves (2x2 of 64x64). LDS linear, XOR-swizzled placement via pre-swizzled
// global source (slot ^= (row>>1)&3) -> 2-way bank aliasing (free) on ds_read.
__global__ __launch_bounds__(256) void gemm_mfma_k(const u16* __restrict__ yb16,
                                                   const u16* __restrict__ x16,
                                                   const u16* __restrict__ Wt,
                                                   const float* __restrict__ bias,
                                                   float* __restrict__ OUT) {
    __shared__ __align__(16) char As[8192];  // 128 rows x 64 B
    __shared__ __align__(16) char Bs[8192];  // 128 cols x 64 B
    const int tid = threadIdx.x;
    const int lane = tid & 63, wid = tid >> 6;
    const int wr = wid >> 1, wc = wid & 1;
    const int bm = blockIdx.x * 128;

    f32x4 acc[4][4] = {};

    // staging geometry: wave stages LDS rows [wid*32, wid*32+32) of As and Bs
    const int r0 = wid * 32;
    const int lrow = lane >> 2;       // 0..15
    const int sphys = lane & 3;       // 16B slot within 64B row
    const int rowL0 = r0 + lrow, rowL1 = r0 + 16 + lrow;
    const int slog0 = (sphys ^ ((rowL0 >> 1) & 3)) * 8;  // element offset
    const int slog1 = (sphys ^ ((rowL1 >> 1) & 3)) * 8;
    int ga0 = bm + rowL0; if (ga0 >= Nn) ga0 = Nn - 1;
    int ga1 = bm + rowL1; if (ga1 >= Nn) ga1 = Nn - 1;

    for (int k0 = 0; k0 < 640; k0 += 32) {
        __syncthreads();
        const u16 *as0, *as1;
        if (k0 < 512) {
            as0 = yb16 + (size_t)ga0 * 512 + k0 + slog0;
            as1 = yb16 + (size_t)ga1 * 512 + k0 + slog1;
        } else {
            as0 = x16 + (size_t)ga0 * 128 + (k0 - 512) + slog0;
            as1 = x16 + (size_t)ga1 * 128 + (k0 - 512) + slog1;
        }
        gload16(as0, &As[r0 * 64]);
        gload16(as1, &As[(r0 + 16) * 64]);
        gload16(Wt + (size_t)rowL0 * 640 + k0 + slog0, &Bs[r0 * 64]);
        gload16(Wt + (size_t)rowL1 * 640 + k0 + slog1, &Bs[(r0 + 16) * 64]);
        __syncthreads();
        s16x8 a[4], b[4];
#pragma unroll
        for (int m = 0; m < 4; m++) {
            int row = wr * 64 + m * 16 + (lane & 15);
            a[m] = *(const s16x8*)&As[row * 64 + (((lane >> 4) ^ ((row >> 1) & 3)) << 4)];
            int col = wc * 64 + m * 16 + (lane & 15);
            b[m] = *(const s16x8*)&Bs[col * 64 + (((lane >> 4) ^ ((col >> 1) & 3)) << 4)];
        }
#pragma unroll
        for (int m = 0; m < 4; m++)
#pragma unroll
            for (int n = 0; n < 4; n++)
                acc[m][n] = __builtin_amdgcn_mfma_f32_16x16x32_bf16(a[m], b[n],
                                                                    acc[m][n], 0, 0, 0);
    }
    // epilogue: D frag layout col=lane&15, row=(lane>>4)*4+e
    float bv[4];
#pragma unroll
    for (int n = 0; n < 4; n++) bv[n] = bias[wc * 64 + n * 16 + (lane & 15)];
#pragma unroll
    for (int m = 0; m < 4; m++) {
        const int rb = bm + wr * 64 + m * 16 + ((lane >> 4) << 2);
#pragma unroll
        for (int e = 0; e < 4; e++) {
            const int r = rb + e;
            if (r < Nn) {
                float* op = OUT + (size_t)r * 128 + wc * 64 + (lane & 15);
#pragma unroll
                for (int n = 0; n < 4; n++) op[n * 16] = fmaxf(acc[m][n][e] + bv[n], 0.f);
            }
        }
    }
}

// ---------------- BN stats ----------------
__global__ __launch_bounds__(256) void stats_k(const float* __restrict__ h,
                                               float* __restrict__ stats) {
    int c = threadIdx.x & 127;
    int rstart = blockIdx.x * 2 + (threadIdx.x >> 7);
    float s = 0.f, s2 = 0.f;
    for (int r = rstart; r < Nn; r += gridDim.x * 2) {
        float v = h[(size_t)r * Dd + c];
        s += v;
        s2 += v * v;
    }
    unsafeAtomicAdd(&stats[c], s);
    unsafeAtomicAdd(&stats[Dd + c], s2);
}

// ---------------- BN normalize (+ optional bf16 emit for next layer) ---------
__global__ __launch_bounds__(256) void norm_k(const float* __restrict__ h,
                                              const float* __restrict__ stats,
                                              const float* __restrict__ gamma,
                                              const float* __restrict__ beta,
                                              float* __restrict__ out,
                                              u16* __restrict__ xb) {
    const float invN = 1.0f / (float)Nn;
    int total = Nn * 32;
    for (int i = blockIdx.x * blockDim.x + threadIdx.x; i < total;
         i += gridDim.x * blockDim.x) {
        int c = (i & 31) * 4;
        float4 v = ((const float4*)h)[i];
        float4 o;
        {
            float mu = stats[c + 0] * invN;
            float var = stats[Dd + c + 0] * invN - mu * mu;
            o.x = gamma[c + 0] * (v.x - mu) * rsqrtf(var + EPSc) + beta[c + 0];
        }
        {
            float mu = stats[c + 1] * invN;
            float var = stats[Dd + c + 1] * invN - mu * mu;
            o.y = gamma[c + 1] * (v.y - mu) * rsqrtf(var + EPSc) + beta[c + 1];
        }
        {
            float mu = stats[c + 2] * invN;
            float var = stats[Dd + c + 2] * invN - mu * mu;
            o.z = gamma[c + 2] * (v.z - mu) * rsqrtf(var + EPSc) + beta[c + 2];
        }
        {
            float mu = stats[c + 3] * invN;
            float var = stats[Dd + c + 3] * invN - mu * mu;
            o.w = gamma[c + 3] * (v.w - mu) * rsqrtf(var + EPSc) + beta[c + 3];
        }
        ((float4*)out)[i] = o;
        if (xb) ((ushort4*)xb)[i] = make_ushort4(f2bf(o.x), f2bf(o.y),
                                                 f2bf(o.z), f2bf(o.w));
    }
}

// ---------------- launch ----------------
extern "C" void kernel_launch(void* const* d_in, const int* in_sizes, int n_in,
                              void* d_out, int out_size, void* d_ws, size_t ws_size,
                              hipStream_t stream) {
    const float* feat = (const float*)d_in[0];
    const int* src = (const int*)d_in[1];
    const int* dst = (const int*)d_in[2];
    const int* et = (const int*)d_in[3];
    float* out = (float*)d_out;

    // workspace (~69.2 MB)
    char* p = (char*)d_ws;
    u16* yb16 = (u16*)p;   p += (size_t)Nn * 512 * 2;                    // 51.2 MB
    u16* x16 = (u16*)p;    p += (size_t)Nn * 128 * 2;                    // 12.8 MB
    u16* Wt = (u16*)p;     p += (size_t)128 * 640 * 2;                   // 160 KB
    int* rowp = (int*)p;   p += ((((size_t)(Nn + 1) * 4) + 15) & ~15ull);
    int2* se = (int2*)p;   p += (size_t)Ee * 8;                          // 4.8 MB
    float* stats = (float*)p;
    int* cursor = (int*)yb16;  // dead before agg_k writes yb16

    // ---- CSR once ----
    hipMemsetAsync(cursor, 0, (size_t)Nn * 4, stream);
    hist_k<<<(Ee + 255) / 256, 256, 0, stream>>>(dst, cursor);
    scan_k<<<1, 1024, 0, stream>>>(cursor, rowp);
    hipMemcpyAsync(cursor, rowp, (size_t)Nn * 4, hipMemcpyDeviceToDevice, stream);
    scatter_k<<<(Ee + 255) / 256, 256, 0, stream>>>(src, dst, et, cursor, se);
    conv_k<<<1024, 256, 0, stream>>>(feat, x16);

    const int gx = (Nn + 127) / 128;  // 391

    for (int l = 0; l < 2; l++) {
        const float* V = (const float*)d_in[4 + 6 * l + 0];
        const float* comb = (const float*)d_in[4 + 6 * l + 1];
        const float* loop = (const float*)d_in[4 + 6 * l + 2];
        const float* bias = (const float*)d_in[4 + 6 * l + 3];
        const float* gamma = (const float*)d_in[4 + 6 * l + 4];
        const float* beta = (const float*)d_in[4 + 6 * l + 5];

        wprep_k<<<(128 * 640 + 255) / 256, 256, 0, stream>>>(V, loop, Wt);
        agg_k<<<(Nn + 3) / 4, 256, 0, stream>>>(x16, se, rowp, comb, yb16);
        hipMemsetAsync(stats, 0, 2 * Dd * sizeof(float), stream);
        gemm_mfma_k<<<gx, 256, 0, stream>>>(yb16, x16, Wt, bias, out);
        stats_k<<<1024, 256, 0, stream>>>(out, stats);
        norm_k<<<2048, 256, 0, stream>>>(out, stats, gamma, beta, out,
                                         (l == 0) ? x16 : nullptr);
    }
}

// Round 5
// 398.435 us; speedup vs baseline: 3.5306x; 1.1992x over previous
//
#include <hip/hip_runtime.h>
#include <hip/hip_bf16.h>

#define Nn 50000
#define Ee 600000
#define Dd 128
#define EPSc 1e-5f

typedef unsigned int u32;
typedef unsigned short u16;
typedef short s16x8 __attribute__((ext_vector_type(8)));
typedef float f32x4 __attribute__((ext_vector_type(4)));

__device__ inline float bf2f(u32 lo16) { return __uint_as_float(lo16 << 16); }
__device__ inline u16 f2bf(float f) {
    u32 b = __float_as_uint(f);
    return (u16)((b + 0x7fffu + ((b >> 16) & 1u)) >> 16);  // RTN-even
}
__device__ inline void gload16(const void* g, void* l) {
    __builtin_amdgcn_global_load_lds(
        (const __attribute__((address_space(1))) u32*)g,
        (__attribute__((address_space(3))) u32*)l, 16, 0, 0);
}

// ---------------- CSR build ----------------
__global__ __launch_bounds__(256) void hist_k(const int* __restrict__ dst,
                                              int* __restrict__ cnt) {
    int e = blockIdx.x * 256 + threadIdx.x;
    if (e < Ee) atomicAdd(&cnt[dst[e]], 1);
}

__global__ __launch_bounds__(1024) void scan_k(const int* __restrict__ cnt,
                                               int* __restrict__ rowp) {
    __shared__ int wsum[16];
    __shared__ int carry_s;
    const int t = threadIdx.x, lane = t & 63, w = t >> 6;
    if (t == 0) { carry_s = 0; rowp[0] = 0; }
    __syncthreads();
    for (int base = 0; base < Nn; base += 1024) {
        int v = (base + t < Nn) ? cnt[base + t] : 0;
        int incl = v;
#pragma unroll
        for (int off = 1; off < 64; off <<= 1) {
            int u = __shfl_up(incl, off, 64);
            if (lane >= off) incl += u;
        }
        if (lane == 63) wsum[w] = incl;
        __syncthreads();
        if (t == 0) {
            int run = carry_s;
#pragma unroll
            for (int i = 0; i < 16; i++) { int s = wsum[i]; wsum[i] = run; run += s; }
            carry_s = run;
        }
        __syncthreads();
        if (base + t < Nn) rowp[base + t + 1] = wsum[w] + incl;
        __syncthreads();
    }
}

__global__ __launch_bounds__(256) void scatter_k(const int* __restrict__ src,
                                                 const int* __restrict__ dst,
                                                 const int* __restrict__ et,
                                                 int* __restrict__ cursor,
                                                 int2* __restrict__ se) {
    int e = blockIdx.x * 256 + threadIdx.x;
    if (e < Ee) {
        int pos = atomicAdd(&cursor[dst[e]], 1);
        se[pos] = make_int2(src[e], et[e]);
    }
}

// ---------------- fp32 -> bf16 convert ----------------
__global__ __launch_bounds__(256) void conv_k(const float* __restrict__ in,
                                              u16* __restrict__ out) {
    const int total = Nn * 32;
    for (int i = blockIdx.x * 256 + threadIdx.x; i < total; i += gridDim.x * 256) {
        float4 v = ((const float4*)in)[i];
        ((ushort4*)out)[i] = make_ushort4(f2bf(v.x), f2bf(v.y), f2bf(v.z), f2bf(v.w));
    }
}

// ---------------- weight prep: Wt[c][k] = W[k][c] in bf16, k: V(512)|loop(128)
__global__ __launch_bounds__(256) void wprep_k(const float* __restrict__ V,
                                               const float* __restrict__ loop,
                                               u16* __restrict__ Wt) {
    int i = blockIdx.x * 256 + threadIdx.x;  // 128*640
    if (i >= 128 * 640) return;
    int c = i / 640, k = i - c * 640;
    float v = (k < 512) ? V[(size_t)k * 128 + c] : loop[(size_t)(k - 512) * 128 + c];
    Wt[i] = f2bf(v);
}

// ---------------- aggregation: yb16[n,b,:] = sum_e comb[et,b]*x16[src] -------
__global__ __launch_bounds__(256) void agg_k(const u16* __restrict__ x16,
                                             const int2* __restrict__ se,
                                             const int* __restrict__ rowp,
                                             const float* __restrict__ comb,
                                             u16* __restrict__ yb16) {
    const int node = blockIdx.x * 4 + (threadIdx.x >> 6);
    const int lane = threadIdx.x & 63;
    const int beg = rowp[node], end = rowp[node + 1];
    float a0x = 0.f, a0y = 0.f, a1x = 0.f, a1y = 0.f;
    float a2x = 0.f, a2y = 0.f, a3x = 0.f, a3y = 0.f;
    int2 rn;
    u32 xn;
    if (beg < end) {
        rn = se[beg];
        xn = *(const u32*)&x16[(size_t)rn.x * 128 + lane * 2];
    }
    for (int e = beg; e < end; e++) {
        const int2 rc = rn;
        const u32 xv = xn;
        if (e + 1 < end) {
            rn = se[e + 1];
            xn = *(const u32*)&x16[(size_t)rn.x * 128 + lane * 2];
        }
        const float4 c = ((const float4*)comb)[rc.y];
        const float fx = bf2f(xv & 0xffffu), fy = bf2f(xv >> 16);
        a0x += c.x * fx; a0y += c.x * fy;
        a1x += c.y * fx; a1y += c.y * fy;
        a2x += c.z * fx; a2y += c.z * fy;
        a3x += c.w * fx; a3y += c.w * fy;
    }
    u32* yp = (u32*)(yb16 + (size_t)node * 512);
    yp[lane]       = (u32)f2bf(a0x) | ((u32)f2bf(a0y) << 16);
    yp[64 + lane]  = (u32)f2bf(a1x) | ((u32)f2bf(a1y) << 16);
    yp[128 + lane] = (u32)f2bf(a2x) | ((u32)f2bf(a2y) << 16);
    yp[192 + lane] = (u32)f2bf(a3x) | ((u32)f2bf(a3y) << 16);
}

// ---------------- MFMA GEMM: OUT = relu([yb16|x16] @ Wt^T + bias) ------------
// + fused BN stats: per-block column partial sums/sumsqs -> shfl-reduce ->
// unsafeAtomicAdd into stats[256] (sum | sumsq). 782 adds/address total.
__global__ __launch_bounds__(256) void gemm_mfma_k(const u16* __restrict__ yb16,
                                                   const u16* __restrict__ x16,
                                                   const u16* __restrict__ Wt,
                                                   const float* __restrict__ bias,
                                                   float* __restrict__ OUT,
                                                   float* __restrict__ stats) {
    __shared__ __align__(16) char As[8192];  // 128 rows x 64 B
    __shared__ __align__(16) char Bs[8192];  // 128 cols x 64 B
    const int tid = threadIdx.x;
    const int lane = tid & 63, wid = tid >> 6;
    const int wr = wid >> 1, wc = wid & 1;
    const int bm = blockIdx.x * 128;

    f32x4 acc[4][4] = {};

    // staging geometry: wave stages LDS rows [wid*32, wid*32+32) of As and Bs
    const int r0 = wid * 32;
    const int lrow = lane >> 2;       // 0..15
    const int sphys = lane & 3;       // 16B slot within 64B row
    const int rowL0 = r0 + lrow, rowL1 = r0 + 16 + lrow;
    const int slog0 = (sphys ^ ((rowL0 >> 1) & 3)) * 8;  // element offset
    const int slog1 = (sphys ^ ((rowL1 >> 1) & 3)) * 8;
    int ga0 = bm + rowL0; if (ga0 >= Nn) ga0 = Nn - 1;
    int ga1 = bm + rowL1; if (ga1 >= Nn) ga1 = Nn - 1;

    for (int k0 = 0; k0 < 640; k0 += 32) {
        __syncthreads();
        const u16 *as0, *as1;
        if (k0 < 512) {
            as0 = yb16 + (size_t)ga0 * 512 + k0 + slog0;
            as1 = yb16 + (size_t)ga1 * 512 + k0 + slog1;
        } else {
            as0 = x16 + (size_t)ga0 * 128 + (k0 - 512) + slog0;
            as1 = x16 + (size_t)ga1 * 128 + (k0 - 512) + slog1;
        }
        gload16(as0, &As[r0 * 64]);
        gload16(as1, &As[(r0 + 16) * 64]);
        gload16(Wt + (size_t)rowL0 * 640 + k0 + slog0, &Bs[r0 * 64]);
        gload16(Wt + (size_t)rowL1 * 640 + k0 + slog1, &Bs[(r0 + 16) * 64]);
        __syncthreads();
        s16x8 a[4], b[4];
#pragma unroll
        for (int m = 0; m < 4; m++) {
            int row = wr * 64 + m * 16 + (lane & 15);
            a[m] = *(const s16x8*)&As[row * 64 + (((lane >> 4) ^ ((row >> 1) & 3)) << 4)];
            int col = wc * 64 + m * 16 + (lane & 15);
            b[m] = *(const s16x8*)&Bs[col * 64 + (((lane >> 4) ^ ((col >> 1) & 3)) << 4)];
        }
#pragma unroll
        for (int m = 0; m < 4; m++)
#pragma unroll
            for (int n = 0; n < 4; n++)
                acc[m][n] = __builtin_amdgcn_mfma_f32_16x16x32_bf16(a[m], b[n],
                                                                    acc[m][n], 0, 0, 0);
    }
    // epilogue: D frag layout col=lane&15, row=(lane>>4)*4+e. Fused BN stats.
    float bv[4], cs[4] = {}, cq[4] = {};
#pragma unroll
    for (int n = 0; n < 4; n++) bv[n] = bias[wc * 64 + n * 16 + (lane & 15)];
#pragma unroll
    for (int m = 0; m < 4; m++) {
        const int rb = bm + wr * 64 + m * 16 + ((lane >> 4) << 2);
#pragma unroll
        for (int e = 0; e < 4; e++) {
            const int r = rb + e;
            if (r < Nn) {
                float* op = OUT + (size_t)r * 128 + wc * 64 + (lane & 15);
#pragma unroll
                for (int n = 0; n < 4; n++) {
                    float v = fmaxf(acc[m][n][e] + bv[n], 0.f);
                    op[n * 16] = v;
                    cs[n] += v;
                    cq[n] += v * v;
                }
            }
        }
    }
    // butterfly over the 4 lanes sharing a column (lane ^ 16, lane ^ 32)
#pragma unroll
    for (int n = 0; n < 4; n++) {
        cs[n] += __shfl_xor(cs[n], 16);
        cs[n] += __shfl_xor(cs[n], 32);
        cq[n] += __shfl_xor(cq[n], 16);
        cq[n] += __shfl_xor(cq[n], 32);
    }
    if (lane < 16) {
#pragma unroll
        for (int n = 0; n < 4; n++) {
            const int col = wc * 64 + n * 16 + lane;
            unsafeAtomicAdd(&stats[col], cs[n]);
            unsafeAtomicAdd(&stats[128 + col], cq[n]);
        }
    }
}

// ---------------- BN normalize (+ optional bf16 emit for next layer) ---------
__global__ __launch_bounds__(256) void norm_k(const float* __restrict__ h,
                                              const float* __restrict__ stats,
                                              const float* __restrict__ gamma,
                                              const float* __restrict__ beta,
                                              float* __restrict__ out,
                                              u16* __restrict__ xb) {
    const float invN = 1.0f / (float)Nn;
    int total = Nn * 32;
    for (int i = blockIdx.x * blockDim.x + threadIdx.x; i < total;
         i += gridDim.x * blockDim.x) {
        int c = (i & 31) * 4;
        float4 v = ((const float4*)h)[i];
        float4 o;
        {
            float mu = stats[c + 0] * invN;
            float var = stats[Dd + c + 0] * invN - mu * mu;
            o.x = gamma[c + 0] * (v.x - mu) * rsqrtf(var + EPSc) + beta[c + 0];
        }
        {
            float mu = stats[c + 1] * invN;
            float var = stats[Dd + c + 1] * invN - mu * mu;
            o.y = gamma[c + 1] * (v.y - mu) * rsqrtf(var + EPSc) + beta[c + 1];
        }
        {
            float mu = stats[c + 2] * invN;
            float var = stats[Dd + c + 2] * invN - mu * mu;
            o.z = gamma[c + 2] * (v.z - mu) * rsqrtf(var + EPSc) + beta[c + 2];
        }
        {
            float mu = stats[c + 3] * invN;
            float var = stats[Dd + c + 3] * invN - mu * mu;
            o.w = gamma[c + 3] * (v.w - mu) * rsqrtf(var + EPSc) + beta[c + 3];
        }
        ((float4*)out)[i] = o;
        if (xb) ((ushort4*)xb)[i] = make_ushort4(f2bf(o.x), f2bf(o.y),
                                                 f2bf(o.z), f2bf(o.w));
    }
}

// ---------------- launch ----------------
extern "C" void kernel_launch(void* const* d_in, const int* in_sizes, int n_in,
                              void* d_out, int out_size, void* d_ws, size_t ws_size,
                              hipStream_t stream) {
    const float* feat = (const float*)d_in[0];
    const int* src = (const int*)d_in[1];
    const int* dst = (const int*)d_in[2];
    const int* et = (const int*)d_in[3];
    float* out = (float*)d_out;

    // workspace (~69.2 MB)
    char* p = (char*)d_ws;
    u16* yb16 = (u16*)p;   p += (size_t)Nn * 512 * 2;                    // 51.2 MB
    u16* x16 = (u16*)p;    p += (size_t)Nn * 128 * 2;                    // 12.8 MB
    u16* Wt = (u16*)p;     p += (size_t)128 * 640 * 2;                   // 160 KB
    int* rowp = (int*)p;   p += ((((size_t)(Nn + 1) * 4) + 15) & ~15ull);
    int2* se = (int2*)p;   p += (size_t)Ee * 8;                          // 4.8 MB
    float* stats = (float*)p;
    int* cursor = (int*)yb16;  // dead before agg_k writes yb16

    // ---- CSR once ----
    hipMemsetAsync(cursor, 0, (size_t)Nn * 4, stream);
    hist_k<<<(Ee + 255) / 256, 256, 0, stream>>>(dst, cursor);
    scan_k<<<1, 1024, 0, stream>>>(cursor, rowp);
    hipMemcpyAsync(cursor, rowp, (size_t)Nn * 4, hipMemcpyDeviceToDevice, stream);
    scatter_k<<<(Ee + 255) / 256, 256, 0, stream>>>(src, dst, et, cursor, se);
    conv_k<<<1024, 256, 0, stream>>>(feat, x16);

    const int gx = (Nn + 127) / 128;  // 391

    for (int l = 0; l < 2; l++) {
        const float* V = (const float*)d_in[4 + 6 * l + 0];
        const float* comb = (const float*)d_in[4 + 6 * l + 1];
        const float* loop = (const float*)d_in[4 + 6 * l + 2];
        const float* bias = (const float*)d_in[4 + 6 * l + 3];
        const float* gamma = (const float*)d_in[4 + 6 * l + 4];
        const float* beta = (const float*)d_in[4 + 6 * l + 5];

        wprep_k<<<(128 * 640 + 255) / 256, 256, 0, stream>>>(V, loop, Wt);
        agg_k<<<(Nn + 3) / 4, 256, 0, stream>>>(x16, se, rowp, comb, yb16);
        hipMemsetAsync(stats, 0, 2 * Dd * sizeof(float), stream);
        gemm_mfma_k<<<gx, 256, 0, stream>>>(yb16, x16, Wt, bias, out, stats);
        norm_k<<<2048, 256, 0, stream>>>(out, stats, gamma, beta, out,
                                         (l == 0) ? x16 : nullptr);
    }
}

// Round 6
// 361.851 us; speedup vs baseline: 3.8875x; 1.1011x over previous
//
#include <hip/hip_runtime.h>
#include <hip/hip_bf16.h>

#define Nn 50000
#define Ee 600000
#define Dd 128
#define EPSc 1e-5f

typedef unsigned int u32;
typedef unsigned short u16;
typedef short s16x8 __attribute__((ext_vector_type(8)));
typedef float f32x4 __attribute__((ext_vector_type(4)));

__device__ inline float bf2f(u32 lo16) { return __uint_as_float(lo16 << 16); }
__device__ inline u16 f2bf(float f) {
    u32 b = __float_as_uint(f);
    return (u16)((b + 0x7fffu + ((b >> 16) & 1u)) >> 16);  // RTN-even
}
__device__ inline void gload16(const void* g, void* l) {
    __builtin_amdgcn_global_load_lds(
        (const __attribute__((address_space(1))) u32*)g,
        (__attribute__((address_space(3))) u32*)l, 16, 0, 0);
}

// ---------------- CSR build ----------------
__global__ __launch_bounds__(256) void hist_k(const int* __restrict__ dst,
                                              int* __restrict__ cnt) {
    int e = blockIdx.x * 256 + threadIdx.x;
    if (e < Ee) atomicAdd(&cnt[dst[e]], 1);
}

__global__ __launch_bounds__(1024) void scan_k(const int* __restrict__ cnt,
                                               int* __restrict__ rowp) {
    __shared__ int wsum[16];
    __shared__ int carry_s;
    const int t = threadIdx.x, lane = t & 63, w = t >> 6;
    if (t == 0) { carry_s = 0; rowp[0] = 0; }
    __syncthreads();
    for (int base = 0; base < Nn; base += 1024) {
        int v = (base + t < Nn) ? cnt[base + t] : 0;
        int incl = v;
#pragma unroll
        for (int off = 1; off < 64; off <<= 1) {
            int u = __shfl_up(incl, off, 64);
            if (lane >= off) incl += u;
        }
        if (lane == 63) wsum[w] = incl;
        __syncthreads();
        if (t == 0) {
            int run = carry_s;
#pragma unroll
            for (int i = 0; i < 16; i++) { int s = wsum[i]; wsum[i] = run; run += s; }
            carry_s = run;
        }
        __syncthreads();
        if (base + t < Nn) rowp[base + t + 1] = wsum[w] + incl;
        __syncthreads();
    }
}

__global__ __launch_bounds__(256) void scatter_k(const int* __restrict__ src,
                                                 const int* __restrict__ dst,
                                                 const int* __restrict__ et,
                                                 int* __restrict__ cursor,
                                                 int2* __restrict__ se) {
    int e = blockIdx.x * 256 + threadIdx.x;
    if (e < Ee) {
        int pos = atomicAdd(&cursor[dst[e]], 1);
        se[pos] = make_int2(src[e], et[e]);
    }
}

// ---------------- fp32 -> bf16 convert ----------------
__global__ __launch_bounds__(256) void conv_k(const float* __restrict__ in,
                                              u16* __restrict__ out) {
    const int total = Nn * 32;
    for (int i = blockIdx.x * 256 + threadIdx.x; i < total; i += gridDim.x * 256) {
        float4 v = ((const float4*)in)[i];
        ((ushort4*)out)[i] = make_ushort4(f2bf(v.x), f2bf(v.y), f2bf(v.z), f2bf(v.w));
    }
}

// ---------------- weight prep: Wt[c][k] = W[k][c] in bf16, k: V(512)|loop(128)
__global__ __launch_bounds__(256) void wprep_k(const float* __restrict__ V,
                                               const float* __restrict__ loop,
                                               u16* __restrict__ Wt) {
    int i = blockIdx.x * 256 + threadIdx.x;  // 128*640
    if (i >= 128 * 640) return;
    int c = i / 640, k = i - c * 640;
    float v = (k < 512) ? V[(size_t)k * 128 + c] : loop[(size_t)(k - 512) * 128 + c];
    Wt[i] = f2bf(v);
}

// ---------------- aggregation: yb16[n,b,:] = sum_e comb[et,b]*x16[src] -------
// 4-deep MLP: 4 independent clamped se loads -> 4 independent x-row gathers
// in flight per wave; tail edges zero-masked on the gathered value.
__global__ __launch_bounds__(256) void agg_k(const u16* __restrict__ x16,
                                             const int2* __restrict__ se,
                                             const int* __restrict__ rowp,
                                             const float* __restrict__ comb,
                                             u16* __restrict__ yb16) {
    const int node = blockIdx.x * 4 + (threadIdx.x >> 6);
    const int lane = threadIdx.x & 63;
    const int beg = rowp[node], end = rowp[node + 1];
    float a0x = 0.f, a0y = 0.f, a1x = 0.f, a1y = 0.f;
    float a2x = 0.f, a2y = 0.f, a3x = 0.f, a3y = 0.f;
    const int eL = end - 1;
    const int co = lane * 2;

    for (int e0 = beg; e0 < end; e0 += 4) {
        const int m = end - e0;
        // 4 independent (clamped) edge-record loads
        const int2 rc0 = se[e0];
        const int2 rc1 = se[min(e0 + 1, eL)];
        const int2 rc2 = se[min(e0 + 2, eL)];
        const int2 rc3 = se[min(e0 + 3, eL)];
        // 4 independent gathers (all addresses valid; tail zero-masked below)
        u32 x0 = *(const u32*)&x16[(size_t)rc0.x * 128 + co];
        u32 x1 = *(const u32*)&x16[(size_t)rc1.x * 128 + co];
        u32 x2 = *(const u32*)&x16[(size_t)rc2.x * 128 + co];
        u32 x3 = *(const u32*)&x16[(size_t)rc3.x * 128 + co];
        if (m < 4) x3 = 0;
        if (m < 3) x2 = 0;
        if (m < 2) x1 = 0;
        const float4 c0 = ((const float4*)comb)[rc0.y];
        const float4 c1 = ((const float4*)comb)[rc1.y];
        const float4 c2 = ((const float4*)comb)[rc2.y];
        const float4 c3 = ((const float4*)comb)[rc3.y];
#define ACC1(c, xv)                                        \
        {                                                  \
            const float fx = bf2f((xv) & 0xffffu);         \
            const float fy = bf2f((xv) >> 16);             \
            a0x += c.x * fx; a0y += c.x * fy;              \
            a1x += c.y * fx; a1y += c.y * fy;              \
            a2x += c.z * fx; a2y += c.z * fy;              \
            a3x += c.w * fx; a3y += c.w * fy;              \
        }
        ACC1(c0, x0)
        ACC1(c1, x1)
        ACC1(c2, x2)
        ACC1(c3, x3)
#undef ACC1
    }
    u32* yp = (u32*)(yb16 + (size_t)node * 512);
    yp[lane]       = (u32)f2bf(a0x) | ((u32)f2bf(a0y) << 16);
    yp[64 + lane]  = (u32)f2bf(a1x) | ((u32)f2bf(a1y) << 16);
    yp[128 + lane] = (u32)f2bf(a2x) | ((u32)f2bf(a2y) << 16);
    yp[192 + lane] = (u32)f2bf(a3x) | ((u32)f2bf(a3y) << 16);
}

// ---------------- MFMA GEMM: OUT = relu([yb16|x16] @ Wt^T + bias) ------------
// + fused BN stats: per-block column partial sums/sumsqs -> shfl-reduce ->
// unsafeAtomicAdd into stats[256] (sum | sumsq). 782 adds/address total.
__global__ __launch_bounds__(256) void gemm_mfma_k(const u16* __restrict__ yb16,
                                                   const u16* __restrict__ x16,
                                                   const u16* __restrict__ Wt,
                                                   const float* __restrict__ bias,
                                                   float* __restrict__ OUT,
                                                   float* __restrict__ stats) {
    __shared__ __align__(16) char As[8192];  // 128 rows x 64 B
    __shared__ __align__(16) char Bs[8192];  // 128 cols x 64 B
    const int tid = threadIdx.x;
    const int lane = tid & 63, wid = tid >> 6;
    const int wr = wid >> 1, wc = wid & 1;
    const int bm = blockIdx.x * 128;

    f32x4 acc[4][4] = {};

    // staging geometry: wave stages LDS rows [wid*32, wid*32+32) of As and Bs
    const int r0 = wid * 32;
    const int lrow = lane >> 2;       // 0..15
    const int sphys = lane & 3;       // 16B slot within 64B row
    const int rowL0 = r0 + lrow, rowL1 = r0 + 16 + lrow;
    const int slog0 = (sphys ^ ((rowL0 >> 1) & 3)) * 8;  // element offset
    const int slog1 = (sphys ^ ((rowL1 >> 1) & 3)) * 8;
    int ga0 = bm + rowL0; if (ga0 >= Nn) ga0 = Nn - 1;
    int ga1 = bm + rowL1; if (ga1 >= Nn) ga1 = Nn - 1;

    for (int k0 = 0; k0 < 640; k0 += 32) {
        __syncthreads();
        const u16 *as0, *as1;
        if (k0 < 512) {
            as0 = yb16 + (size_t)ga0 * 512 + k0 + slog0;
            as1 = yb16 + (size_t)ga1 * 512 + k0 + slog1;
        } else {
            as0 = x16 + (size_t)ga0 * 128 + (k0 - 512) + slog0;
            as1 = x16 + (size_t)ga1 * 128 + (k0 - 512) + slog1;
        }
        gload16(as0, &As[r0 * 64]);
        gload16(as1, &As[(r0 + 16) * 64]);
        gload16(Wt + (size_t)rowL0 * 640 + k0 + slog0, &Bs[r0 * 64]);
        gload16(Wt + (size_t)rowL1 * 640 + k0 + slog1, &Bs[(r0 + 16) * 64]);
        __syncthreads();
        s16x8 a[4], b[4];
#pragma unroll
        for (int m = 0; m < 4; m++) {
            int row = wr * 64 + m * 16 + (lane & 15);
            a[m] = *(const s16x8*)&As[row * 64 + (((lane >> 4) ^ ((row >> 1) & 3)) << 4)];
            int col = wc * 64 + m * 16 + (lane & 15);
            b[m] = *(const s16x8*)&Bs[col * 64 + (((lane >> 4) ^ ((col >> 1) & 3)) << 4)];
        }
#pragma unroll
        for (int m = 0; m < 4; m++)
#pragma unroll
            for (int n = 0; n < 4; n++)
                acc[m][n] = __builtin_amdgcn_mfma_f32_16x16x32_bf16(a[m], b[n],
                                                                    acc[m][n], 0, 0, 0);
    }
    // epilogue: D frag layout col=lane&15, row=(lane>>4)*4+e. Fused BN stats.
    float bv[4], cs[4] = {}, cq[4] = {};
#pragma unroll
    for (int n = 0; n < 4; n++) bv[n] = bias[wc * 64 + n * 16 + (lane & 15)];
#pragma unroll
    for (int m = 0; m < 4; m++) {
        const int rb = bm + wr * 64 + m * 16 + ((lane >> 4) << 2);
#pragma unroll
        for (int e = 0; e < 4; e++) {
            const int r = rb + e;
            if (r < Nn) {
                float* op = OUT + (size_t)r * 128 + wc * 64 + (lane & 15);
#pragma unroll
                for (int n = 0; n < 4; n++) {
                    float v = fmaxf(acc[m][n][e] + bv[n], 0.f);
                    op[n * 16] = v;
                    cs[n] += v;
                    cq[n] += v * v;
                }
            }
        }
    }
    // butterfly over the 4 lanes sharing a column (lane ^ 16, lane ^ 32)
#pragma unroll
    for (int n = 0; n < 4; n++) {
        cs[n] += __shfl_xor(cs[n], 16);
        cs[n] += __shfl_xor(cs[n], 32);
        cq[n] += __shfl_xor(cq[n], 16);
        cq[n] += __shfl_xor(cq[n], 32);
    }
    if (lane < 16) {
#pragma unroll
        for (int n = 0; n < 4; n++) {
            const int col = wc * 64 + n * 16 + lane;
            unsafeAtomicAdd(&stats[col], cs[n]);
            unsafeAtomicAdd(&stats[128 + col], cq[n]);
        }
    }
}

// ---------------- BN normalize (+ optional bf16 emit for next layer) ---------
__global__ __launch_bounds__(256) void norm_k(const float* __restrict__ h,
                                              const float* __restrict__ stats,
                                              const float* __restrict__ gamma,
                                              const float* __restrict__ beta,
                                              float* __restrict__ out,
                                              u16* __restrict__ xb) {
    const float invN = 1.0f / (float)Nn;
    int total = Nn * 32;
    for (int i = blockIdx.x * blockDim.x + threadIdx.x; i < total;
         i += gridDim.x * blockDim.x) {
        int c = (i & 31) * 4;
        float4 v = ((const float4*)h)[i];
        float4 o;
        {
            float mu = stats[c + 0] * invN;
            float var = stats[Dd + c + 0] * invN - mu * mu;
            o.x = gamma[c + 0] * (v.x - mu) * rsqrtf(var + EPSc) + beta[c + 0];
        }
        {
            float mu = stats[c + 1] * invN;
            float var = stats[Dd + c + 1] * invN - mu * mu;
            o.y = gamma[c + 1] * (v.y - mu) * rsqrtf(var + EPSc) + beta[c + 1];
        }
        {
            float mu = stats[c + 2] * invN;
            float var = stats[Dd + c + 2] * invN - mu * mu;
            o.z = gamma[c + 2] * (v.z - mu) * rsqrtf(var + EPSc) + beta[c + 2];
        }
        {
            float mu = stats[c + 3] * invN;
            float var = stats[Dd + c + 3] * invN - mu * mu;
            o.w = gamma[c + 3] * (v.w - mu) * rsqrtf(var + EPSc) + beta[c + 3];
        }
        ((float4*)out)[i] = o;
        if (xb) ((ushort4*)xb)[i] = make_ushort4(f2bf(o.x), f2bf(o.y),
                                                 f2bf(o.z), f2bf(o.w));
    }
}

// ---------------- launch ----------------
extern "C" void kernel_launch(void* const* d_in, const int* in_sizes, int n_in,
                              void* d_out, int out_size, void* d_ws, size_t ws_size,
                              hipStream_t stream) {
    const float* feat = (const float*)d_in[0];
    const int* src = (const int*)d_in[1];
    const int* dst = (const int*)d_in[2];
    const int* et = (const int*)d_in[3];
    float* out = (float*)d_out;

    // workspace (~69.2 MB)
    char* p = (char*)d_ws;
    u16* yb16 = (u16*)p;   p += (size_t)Nn * 512 * 2;                    // 51.2 MB
    u16* x16 = (u16*)p;    p += (size_t)Nn * 128 * 2;                    // 12.8 MB
    u16* Wt = (u16*)p;     p += (size_t)128 * 640 * 2;                   // 160 KB
    int* rowp = (int*)p;   p += ((((size_t)(Nn + 1) * 4) + 15) & ~15ull);
    int2* se = (int2*)p;   p += (size_t)Ee * 8;                          // 4.8 MB
    float* stats = (float*)p;
    int* cursor = (int*)yb16;  // dead before agg_k writes yb16

    // ---- CSR once ----
    hipMemsetAsync(cursor, 0, (size_t)Nn * 4, stream);
    hist_k<<<(Ee + 255) / 256, 256, 0, stream>>>(dst, cursor);
    scan_k<<<1, 1024, 0, stream>>>(cursor, rowp);
    hipMemcpyAsync(cursor, rowp, (size_t)Nn * 4, hipMemcpyDeviceToDevice, stream);
    scatter_k<<<(Ee + 255) / 256, 256, 0, stream>>>(src, dst, et, cursor, se);
    conv_k<<<1024, 256, 0, stream>>>(feat, x16);

    const int gx = (Nn + 127) / 128;  // 391

    for (int l = 0; l < 2; l++) {
        const float* V = (const float*)d_in[4 + 6 * l + 0];
        const float* comb = (const float*)d_in[4 + 6 * l + 1];
        const float* loop = (const float*)d_in[4 + 6 * l + 2];
        const float* bias = (const float*)d_in[4 + 6 * l + 3];
        const float* gamma = (const float*)d_in[4 + 6 * l + 4];
        const float* beta = (const float*)d_in[4 + 6 * l + 5];

        wprep_k<<<(128 * 640 + 255) / 256, 256, 0, stream>>>(V, loop, Wt);
        agg_k<<<(Nn + 3) / 4, 256, 0, stream>>>(x16, se, rowp, comb, yb16);
        hipMemsetAsync(stats, 0, 2 * Dd * sizeof(float), stream);
        gemm_mfma_k<<<gx, 256, 0, stream>>>(yb16, x16, Wt, bias, out, stats);
        norm_k<<<2048, 256, 0, stream>>>(out, stats, gamma, beta, out,
                                         (l == 0) ? x16 : nullptr);
    }
}